// Round 8
// baseline (267.993 us; speedup 1.0000x reference)
//
#include <hip/hip_runtime.h>
#include <hip/hip_bf16.h>

typedef unsigned short ushort_t;
typedef __attribute__((ext_vector_type(8))) short s16x8;
typedef __attribute__((ext_vector_type(4))) float f32x4;

__device__ inline unsigned short f2bf(float x) {
    unsigned u = __float_as_uint(x);
    return (unsigned short)((u + 0x7FFFu + ((u >> 16) & 1u)) >> 16);
}
__device__ inline float bflo(unsigned u) { return __uint_as_float(u << 16); }
__device__ inline float bfhi(unsigned u) { return __uint_as_float(u & 0xffff0000u); }

// ---------------------------------------------------------------------------
// convert_w: pack weights into MFMA B-fragment order (bf16). Also zeroes counts.
// ---------------------------------------------------------------------------
__device__ inline void pack_one(const float* __restrict__ W, int K, int N,
                                ushort_t* __restrict__ dst, int g) {
    int KT = K / 32;
    int nt = g / (KT * 64);
    int rem = g % (KT * 64);
    int kt = rem / 64, lane = rem % 64;
    int n = nt * 16 + (lane & 15);
    int kbase = kt * 32 + ((lane >> 4) << 3);
    ushort_t tmp[8];
#pragma unroll
    for (int j = 0; j < 8; ++j) tmp[j] = f2bf(W[(size_t)(kbase + j) * N + n]);
    uint4 pk;
    pk.x = tmp[0] | ((unsigned)tmp[1] << 16);
    pk.y = tmp[2] | ((unsigned)tmp[3] << 16);
    pk.z = tmp[4] | ((unsigned)tmp[5] << 16);
    pk.w = tmp[6] | ((unsigned)tmp[7] << 16);
    *(uint4*)&dst[(size_t)g * 8] = pk;
}

__global__ void convert_w(const float* __restrict__ Wn, const float* __restrict__ W1,
                          const float* __restrict__ Wu, const float* __restrict__ Wy1,
                          const float* __restrict__ Wa1,
                          ushort_t* __restrict__ Wnb, ushort_t* __restrict__ W1tb,
                          ushort_t* __restrict__ W1mb, ushort_t* __restrict__ Wub,
                          ushort_t* __restrict__ Wy1b, ushort_t* __restrict__ Wa1b,
                          int* __restrict__ counts, int N) {
    int t = blockIdx.x * 256 + threadIdx.x;
    if (t < 1024)       pack_one(Wn, 64, 128, Wnb, t);
    else if (t < 3072)  pack_one(W1, 128, 128, W1tb, t - 1024);
    else if (t < 5120)  pack_one(W1 + 128 * 128, 128, 128, W1mb, t - 3072);
    else if (t < 7168)  pack_one(Wu, 128, 128, Wub, t - 5120);
    else if (t < 8192)  pack_one(Wy1, 128, 64, Wy1b, t - 7168);
    else if (t < 9216)  pack_one(Wa1, 128, 64, Wa1b, t - 8192);
    if (t < N) counts[t] = 0;
}

// ---------------------------------------------------------------------------
// encode_pq: 64 rows/block, wave owns 16 rows. h,Q interleaved per node in QH
// (QH[n] = [Q_row(128) | h_row(128)]). P separate. Fused dst histogram.
// ---------------------------------------------------------------------------
__global__ void encode_pq(const float* __restrict__ x, const ushort_t* __restrict__ Wnb,
                          const float* __restrict__ bn, const ushort_t* __restrict__ W1tb,
                          const ushort_t* __restrict__ W1mb, const float* __restrict__ b1,
                          ushort_t* __restrict__ QH, ushort_t* __restrict__ P,
                          const int* __restrict__ dst, int* __restrict__ counts,
                          int nrows, int E) {
    __shared__ ushort_t ldsH[4 * 16 * 136];
    int t = threadIdx.x;
    // fused dst histogram (grid-stride)
    for (int e = blockIdx.x * 256 + t; e < E; e += gridDim.x * 256)
        atomicAdd(&counts[dst[e]], 1);
    int w = t >> 6, lane = t & 63;
    int c = lane & 15, q = lane >> 4;
    int r0 = blockIdx.x * 64 + w * 16;
    int rowA = r0 + c; if (rowA >= nrows) rowA = nrows - 1;
    ushort_t* myH = &ldsH[w * 16 * 136];

    s16x8 xa[2];
#pragma unroll
    for (int kt = 0; kt < 2; ++kt) {
        const float* xp = &x[(size_t)rowA * 64 + kt * 32 + q * 8];
        float4 v0 = *(const float4*)xp;
        float4 v1 = *(const float4*)(xp + 4);
        s16x8 a;
        a[0] = (short)f2bf(v0.x); a[1] = (short)f2bf(v0.y);
        a[2] = (short)f2bf(v0.z); a[3] = (short)f2bf(v0.w);
        a[4] = (short)f2bf(v1.x); a[5] = (short)f2bf(v1.y);
        a[6] = (short)f2bf(v1.z); a[7] = (short)f2bf(v1.w);
        xa[kt] = a;
    }
#pragma unroll
    for (int nt = 0; nt < 8; ++nt) {
        f32x4 acc = {0.f, 0.f, 0.f, 0.f};
#pragma unroll
        for (int kt = 0; kt < 2; ++kt) {
            s16x8 b = *(const s16x8*)&Wnb[((nt * 2 + kt) * 64 + lane) * 8];
            acc = __builtin_amdgcn_mfma_f32_16x16x32_bf16(xa[kt], b, acc, 0, 0, 0);
        }
        float bi = bn[nt * 16 + c];
#pragma unroll
        for (int r = 0; r < 4; ++r) {
            int row = r0 + q * 4 + r;
            ushort_t hv = f2bf(acc[r] + bi);
            myH[(q * 4 + r) * 136 + nt * 16 + c] = hv;
            if (row < nrows) QH[(size_t)row * 256 + 128 + nt * 16 + c] = hv;  // h half
        }
    }
    __syncthreads();
    s16x8 ha[4];
#pragma unroll
    for (int kt = 0; kt < 4; ++kt)
        ha[kt] = *(const s16x8*)&myH[c * 136 + kt * 32 + q * 8];
#pragma unroll
    for (int nt = 0; nt < 8; ++nt) {
        f32x4 pa = {0.f, 0.f, 0.f, 0.f}, qa = pa;
#pragma unroll
        for (int kt = 0; kt < 4; ++kt) {
            s16x8 bp = *(const s16x8*)&W1tb[((nt * 4 + kt) * 64 + lane) * 8];
            s16x8 bq = *(const s16x8*)&W1mb[((nt * 4 + kt) * 64 + lane) * 8];
            pa = __builtin_amdgcn_mfma_f32_16x16x32_bf16(ha[kt], bp, pa, 0, 0, 0);
            qa = __builtin_amdgcn_mfma_f32_16x16x32_bf16(ha[kt], bq, qa, 0, 0, 0);
        }
        float bi = b1[nt * 16 + c];
#pragma unroll
        for (int r = 0; r < 4; ++r) {
            int row = r0 + q * 4 + r;
            if (row < nrows) {
                P[(size_t)row * 128 + nt * 16 + c] = f2bf(pa[r] + bi);
                QH[(size_t)row * 256 + nt * 16 + c] = f2bf(qa[r]);  // Q half
            }
        }
    }
}

// ---------------------------------------------------------------------------
// CSR scan: scan1 + scan_add
// ---------------------------------------------------------------------------
__global__ void scan1(const int* __restrict__ counts, int* __restrict__ offs,
                      int* __restrict__ partials, int N) {
    __shared__ int sm[256];
    int i = blockIdx.x * 256 + threadIdx.x;
    int v = (i < N) ? counts[i] : 0;
    sm[threadIdx.x] = v; __syncthreads();
    for (int off = 1; off < 256; off <<= 1) {
        int add = (threadIdx.x >= off) ? sm[threadIdx.x - off] : 0;
        __syncthreads();
        sm[threadIdx.x] += add;
        __syncthreads();
    }
    if (i < N) offs[i] = sm[threadIdx.x] - v;
    if (threadIdx.x == 255) partials[blockIdx.x] = sm[255];
}

__global__ void scan_add(int* __restrict__ offs, int* __restrict__ cursor,
                         const int* __restrict__ partials, int nb, int N) {
    __shared__ int sm[256];
    int t = threadIdx.x;
    sm[t] = (t < nb && t < blockIdx.x) ? partials[t] : 0;
    __syncthreads();
    for (int off = 128; off > 0; off >>= 1) {
        if (t < off) sm[t] += sm[t + off];
        __syncthreads();
    }
    int basev = sm[0];
    int i = blockIdx.x * 256 + t;
    if (i < N) {
        int v = offs[i] + basev;
        offs[i] = v;
        cursor[i] = v;
    }
}

__global__ void fill_csr(const int* __restrict__ src, const int* __restrict__ dst,
                         int* __restrict__ cursor, int* __restrict__ csrc, int E) {
    int e = blockIdx.x * 256 + threadIdx.x;
    if (e >= E) return;
    int p = atomicAdd(&cursor[dst[e]], 1);
    csrc[p] = src[e];
}

// ---------------------------------------------------------------------------
// fused_gather: score + per-node online softmax + h-gather in ONE CSR pass.
// 16 nodes/block, wave per 4 nodes, quarter-wave per edge (4 in flight).
// Writes A_n (bf16 unnormalized aggregate), m_n, and per-block (m,Z) partials.
// ---------------------------------------------------------------------------
__global__ void fused_gather(const ushort_t* __restrict__ P, const ushort_t* __restrict__ QH,
                             const float* __restrict__ pos, const int* __restrict__ csrc,
                             const int* __restrict__ offs, const int* __restrict__ deg,
                             const float* __restrict__ W1b, const float* __restrict__ W2,
                             const float* __restrict__ b2,
                             ushort_t* __restrict__ A_out, float* __restrict__ m_out,
                             float* __restrict__ redm, float* __restrict__ rede, int N) {
    __shared__ float wsh[512];
    __shared__ float smm[256], sme[256];
    int t = threadIdx.x;
    for (int i = t; i < 384; i += 256) wsh[i] = W1b[i];
    if (t < 128) wsh[384 + t] = W2[t];
    __syncthreads();
    int w = t >> 6, lane = t & 63;
    int g = lane >> 4, c = lane & 15;
    float w0[8], w1[8], w2[8], wv[8];
#pragma unroll
    for (int j = 0; j < 8; ++j) {
        w0[j] = wsh[c * 8 + j];
        w1[j] = wsh[128 + c * 8 + j];
        w2[j] = wsh[256 + c * 8 + j];
        wv[j] = wsh[384 + c * 8 + j];
    }
    float b2v = b2[0];
    float mB = -1e30f, zB = 0.f;   // per-thread block partial (only lane g==0,c==0 feeds)
#pragma unroll
    for (int i = 0; i < 4; ++i) {
        int node = blockIdx.x * 16 + w * 4 + i;
        float m = -1e30f, z = 0.f;
        float a[8] = {0.f, 0.f, 0.f, 0.f, 0.f, 0.f, 0.f, 0.f};
        if (node < N) {
            uint4 pr = *(const uint4*)&P[(size_t)node * 128 + c * 8];
            float pv[8];
            pv[0] = bflo(pr.x); pv[1] = bfhi(pr.x); pv[2] = bflo(pr.y); pv[3] = bfhi(pr.y);
            pv[4] = bflo(pr.z); pv[5] = bfhi(pr.z); pv[6] = bflo(pr.w); pv[7] = bfhi(pr.w);
            float pd0 = pos[node * 3], pd1 = pos[node * 3 + 1], pd2 = pos[node * 3 + 2];
            int start = offs[node], d = deg[node];
            for (int k = g; k < d; k += 4) {
                int sa = csrc[start + k];
                const ushort_t* qhp = &QH[(size_t)sa * 256 + c * 8];
                uint4 qr = *(const uint4*)qhp;
                uint4 hr = *(const uint4*)(qhp + 128);
                float d0 = pd0 - pos[sa * 3];
                float d1 = pd1 - pos[sa * 3 + 1];
                float d2 = pd2 - pos[sa * 3 + 2];
                unsigned qw[4] = {qr.x, qr.y, qr.z, qr.w};
                float v = 0.f;
#pragma unroll
                for (int jj = 0; jj < 4; ++jj) {
                    float pe = pv[2 * jj] + bflo(qw[jj])
                             + d0 * w0[2 * jj] + d1 * w1[2 * jj] + d2 * w2[2 * jj];
                    float po = pv[2 * jj + 1] + bfhi(qw[jj])
                             + d0 * w0[2 * jj + 1] + d1 * w1[2 * jj + 1] + d2 * w2[2 * jj + 1];
                    v += fmaxf(pe, 0.f) * wv[2 * jj] + fmaxf(po, 0.f) * wv[2 * jj + 1];
                }
#pragma unroll
                for (int off = 1; off < 16; off <<= 1) v += __shfl_xor(v, off, 64);
                float s = v + b2v;
                float nm = fmaxf(m, s);
                float f  = __expf(m - nm);
                float es = __expf(s - nm);
                z = z * f + es;
                m = nm;
                float hv[8];
                hv[0] = bflo(hr.x); hv[1] = bfhi(hr.x); hv[2] = bflo(hr.y); hv[3] = bfhi(hr.y);
                hv[4] = bflo(hr.z); hv[5] = bfhi(hr.z); hv[6] = bflo(hr.w); hv[7] = bfhi(hr.w);
#pragma unroll
                for (int j = 0; j < 8; ++j) a[j] = a[j] * f + hv[j] * es;
            }
        }
        // combine 4 quarter-waves (all lanes participate)
#pragma unroll
        for (int off = 16; off <= 32; off <<= 1) {
            float m2 = __shfl_xor(m, off, 64);
            float z2 = __shfl_xor(z, off, 64);
            float M = fmaxf(m, m2);
            float e1 = __expf(m - M), e2 = __expf(m2 - M);
#pragma unroll
            for (int j = 0; j < 8; ++j) {
                float a2 = __shfl_xor(a[j], off, 64);
                a[j] = a[j] * e1 + a2 * e2;
            }
            z = z * e1 + z2 * e2;
            m = M;
        }
        if (g == 0 && node < N) {
            uint4 pk;
            pk.x = f2bf(a[0]) | ((unsigned)f2bf(a[1]) << 16);
            pk.y = f2bf(a[2]) | ((unsigned)f2bf(a[3]) << 16);
            pk.z = f2bf(a[4]) | ((unsigned)f2bf(a[5]) << 16);
            pk.w = f2bf(a[6]) | ((unsigned)f2bf(a[7]) << 16);
            *(uint4*)&A_out[(size_t)node * 128 + c * 8] = pk;
            if (c == 0) {
                m_out[node] = m;
                float M = fmaxf(mB, m);
                float e1 = __expf(mB - M), e2 = __expf(m - M);
                zB = zB * e1 + z * e2;
                mB = M;
            }
        }
    }
    smm[t] = mB; sme[t] = zB; __syncthreads();
    for (int off = 128; off > 0; off >>= 1) {
        if (t < off) {
            float m1 = smm[t], m2 = smm[t + off];
            float e1 = sme[t], e2 = sme[t + off];
            float M = fmaxf(m1, m2);
            smm[t] = M;
            sme[t] = e1 * __expf(m1 - M) + e2 * __expf(m2 - M);
        }
        __syncthreads();
    }
    if (t == 0) { redm[blockIdx.x] = smm[0]; rede[blockIdx.x] = sme[0]; }
}

// single block combines nb (m,Z) partials -> scal = {M, 1/Z_global}
__global__ void combine(const float* __restrict__ redm, const float* __restrict__ rede,
                        float* __restrict__ scal, int nb) {
    __shared__ float smm[256], sme[256];
    int t = threadIdx.x;
    float m = -1e30f, ev = 0.f;
    for (int i = t; i < nb; i += 256) {
        float m2 = redm[i], e2 = rede[i];
        float M = fmaxf(m, m2);
        ev = ev * __expf(m - M) + e2 * __expf(m2 - M);
        m = M;
    }
    smm[t] = m; sme[t] = ev; __syncthreads();
    for (int off = 128; off > 0; off >>= 1) {
        if (t < off) {
            float m1 = smm[t], m2 = smm[t + off];
            float e1 = sme[t], e2 = sme[t + off];
            float M = fmaxf(m1, m2);
            smm[t] = M;
            sme[t] = e1 * __expf(m1 - M) + e2 * __expf(m2 - M);
        }
        __syncthreads();
    }
    if (t == 0) { scal[0] = smm[0]; scal[1] = 1.f / sme[0]; }
}

// ---------------------------------------------------------------------------
// upd_mfma: mol_feats[row] = scale(row) * (A_row @ Wu) + bu,
// scale(row) = exp(m_n[row] - M) / Z_global.  16 rows/block.
// ---------------------------------------------------------------------------
__global__ void upd_mfma(const ushort_t* __restrict__ A, const float* __restrict__ m_n,
                         const float* __restrict__ scal,
                         const ushort_t* __restrict__ Wub, const float* __restrict__ bu,
                         float* __restrict__ C, int N) {
    __shared__ ushort_t ldsA[16 * 136];
    int t = threadIdx.x;
    int r0 = blockIdx.x * 16;
    {
        int row = t >> 4, c8 = (t & 15) * 8;
        *(uint4*)&ldsA[row * 136 + c8] = *(const uint4*)&A[(size_t)(r0 + row) * 128 + c8];
    }
    __syncthreads();
    int w = t >> 6, lane = t & 63;
    int c = lane & 15, q = lane >> 4;
    int ntA = w, ntB = w + 4;
    f32x4 acc0 = {0.f, 0.f, 0.f, 0.f}, acc1 = acc0;
#pragma unroll
    for (int kt = 0; kt < 4; ++kt) {
        s16x8 av = *(const s16x8*)&ldsA[c * 136 + kt * 32 + q * 8];
        s16x8 b0 = *(const s16x8*)&Wub[((ntA * 4 + kt) * 64 + lane) * 8];
        s16x8 b1 = *(const s16x8*)&Wub[((ntB * 4 + kt) * 64 + lane) * 8];
        acc0 = __builtin_amdgcn_mfma_f32_16x16x32_bf16(av, b0, acc0, 0, 0, 0);
        acc1 = __builtin_amdgcn_mfma_f32_16x16x32_bf16(av, b1, acc1, 0, 0, 0);
    }
    float M = scal[0], invZ = scal[1];
    float bi0 = bu[ntA * 16 + c], bi1 = bu[ntB * 16 + c];
#pragma unroll
    for (int r = 0; r < 4; ++r) {
        int row = r0 + q * 4 + r;
        if (row < N) {
            float sc = __expf(m_n[row] - M) * invZ;
            C[(size_t)row * 128 + ntA * 16 + c] = acc0[r] * sc + bi0;
            C[(size_t)row * 128 + ntB * 16 + c] = acc1[r] * sc + bi1;
        }
    }
}

// ---------------------------------------------------------------------------
// head_mfma: out[r] = relu((x@Wn+bn)@W1+b1) . W2 + b2, fused, 16 rows/block
// ---------------------------------------------------------------------------
__global__ void head_mfma(const float* __restrict__ rx, const float* __restrict__ tx,
                          const ushort_t* __restrict__ Wnb, const float* __restrict__ bn,
                          const ushort_t* __restrict__ Wy1b, const float* __restrict__ by1,
                          const float* __restrict__ Wy2, const float* __restrict__ by2,
                          const ushort_t* __restrict__ Wa1b, const float* __restrict__ ba1,
                          const float* __restrict__ Wa2, const float* __restrict__ ba2,
                          float* __restrict__ out, int nb1, int NR, int NT) {
    __shared__ ushort_t ldsA[16 * 72];
    __shared__ ushort_t ldsB[16 * 136];
    __shared__ float part[64];
    int blk = blockIdx.x;
    const float* x; const ushort_t* W1b; const float* b1; const float* W2; const float* b2;
    float* o; int r0, nrows;
    if (blk < nb1) { x = rx; W1b = Wy1b; b1 = by1; W2 = Wy2; b2 = by2; o = out; r0 = blk * 16; nrows = NR; }
    else { x = tx; W1b = Wa1b; b1 = ba1; W2 = Wa2; b2 = ba2; o = out + NR; r0 = (blk - nb1) * 16; nrows = NT; }

    int t = threadIdx.x;
    {
        int row = t >> 4, c4 = (t & 15) * 4;
        float4 v = *(const float4*)&x[(size_t)(r0 + row) * 64 + c4];
        uint2 pk;
        pk.x = f2bf(v.x) | ((unsigned)f2bf(v.y) << 16);
        pk.y = f2bf(v.z) | ((unsigned)f2bf(v.w) << 16);
        *(uint2*)&ldsA[row * 72 + c4] = pk;
    }
    __syncthreads();
    int w = t >> 6, lane = t & 63;
    int c = lane & 15, q = lane >> 4;
    {
        int ntA = w, ntB = w + 4;
        f32x4 acc0 = {0.f, 0.f, 0.f, 0.f}, acc1 = acc0;
#pragma unroll
        for (int kt = 0; kt < 2; ++kt) {
            s16x8 a = *(const s16x8*)&ldsA[c * 72 + kt * 32 + q * 8];
            s16x8 b0 = *(const s16x8*)&Wnb[((ntA * 2 + kt) * 64 + lane) * 8];
            s16x8 b1v = *(const s16x8*)&Wnb[((ntB * 2 + kt) * 64 + lane) * 8];
            acc0 = __builtin_amdgcn_mfma_f32_16x16x32_bf16(a, b0, acc0, 0, 0, 0);
            acc1 = __builtin_amdgcn_mfma_f32_16x16x32_bf16(a, b1v, acc1, 0, 0, 0);
        }
        float bi0 = bn[ntA * 16 + c], bi1 = bn[ntB * 16 + c];
#pragma unroll
        for (int r = 0; r < 4; ++r) {
            int row = q * 4 + r;
            ldsB[row * 136 + ntA * 16 + c] = f2bf(acc0[r] + bi0);
            ldsB[row * 136 + ntB * 16 + c] = f2bf(acc1[r] + bi1);
        }
    }
    __syncthreads();
    {
        f32x4 acc = {0.f, 0.f, 0.f, 0.f};
#pragma unroll
        for (int kt = 0; kt < 4; ++kt) {
            s16x8 a = *(const s16x8*)&ldsB[c * 136 + kt * 32 + q * 8];
            s16x8 b0 = *(const s16x8*)&W1b[((w * 4 + kt) * 64 + lane) * 8];
            acc = __builtin_amdgcn_mfma_f32_16x16x32_bf16(a, b0, acc, 0, 0, 0);
        }
        float bi = b1[w * 16 + c], w2v = W2[w * 16 + c];
#pragma unroll
        for (int r = 0; r < 4; ++r) {
            float u = fmaxf(acc[r] + bi, 0.f) * w2v;
#pragma unroll
            for (int mm = 1; mm < 16; mm <<= 1) u += __shfl_xor(u, mm, 64);
            if (c == 0) part[w * 16 + q * 4 + r] = u;
        }
    }
    __syncthreads();
    if (t < 16) {
        int row = r0 + t;
        if (row < nrows)
            o[row] = part[t] + part[16 + t] + part[32 + t] + part[48 + t] + b2[0];
    }
}

extern "C" void kernel_launch(void* const* d_in, const int* in_sizes, int n_in,
                              void* d_out, int out_size, void* d_ws, size_t ws_size,
                              hipStream_t stream) {
    const float* mol_x      = (const float*)d_in[0];
    const float* pos        = (const float*)d_in[1];
    const float* reaction_x = (const float*)d_in[2];
    const float* target_x   = (const float*)d_in[3];
    const int*   ei         = (const int*)d_in[4];
    const float* W_node = (const float*)d_in[5];
    const float* b_node = (const float*)d_in[6];
    const float* W_att1 = (const float*)d_in[7];
    const float* b_att1 = (const float*)d_in[8];
    const float* W_att2 = (const float*)d_in[9];
    const float* b_att2 = (const float*)d_in[10];
    const float* W_upd  = (const float*)d_in[11];
    const float* b_upd  = (const float*)d_in[12];
    const float* Wy1 = (const float*)d_in[13];
    const float* by1 = (const float*)d_in[14];
    const float* Wy2 = (const float*)d_in[15];
    const float* by2 = (const float*)d_in[16];
    const float* Wa1 = (const float*)d_in[17];
    const float* ba1 = (const float*)d_in[18];
    const float* Wa2 = (const float*)d_in[19];
    const float* ba2 = (const float*)d_in[20];

    int N  = in_sizes[0] / 64;
    int E  = in_sizes[4] / 2;
    int NR = in_sizes[2] / 64;
    int NT = in_sizes[3] / 64;

    float* out = (float*)d_out;

    int nbG = (N + 15) / 16;     // fused_gather blocks / softmax partials

    // ws layout
    char* wp = (char*)d_ws;
    ushort_t* QH = (ushort_t*)wp;  wp += (size_t)N * 256 * 2;
    ushort_t* Ab = (ushort_t*)wp;  wp += (size_t)N * 128 * 2;
    float* m_n   = (float*)wp;     wp += (size_t)N * 4;
    float* redm  = (float*)wp;     wp += (size_t)nbG * 4;
    float* rede  = (float*)wp;     wp += (size_t)nbG * 4;
    float* scal  = (float*)wp;     wp += 4 * 4;
    int* counts  = (int*)wp;       wp += (size_t)N * 4;
    int* offs    = (int*)wp;       wp += (size_t)N * 4;
    int* cursor  = (int*)wp;       wp += (size_t)N * 4;
    int* partials= (int*)wp;       wp += 256 * 4;
    int* csrc    = (int*)wp;       wp += (size_t)E * 4;
    ushort_t* Wnb  = (ushort_t*)wp; wp += 8192 * 2;
    ushort_t* W1tb = (ushort_t*)wp; wp += 16384 * 2;
    ushort_t* W1mb = (ushort_t*)wp; wp += 16384 * 2;
    ushort_t* Wub  = (ushort_t*)wp; wp += 16384 * 2;
    ushort_t* Wy1b = (ushort_t*)wp; wp += 8192 * 2;
    ushort_t* Wa1b = (ushort_t*)wp; wp += 8192 * 2;
    // P lives in the mol_feats output region (dead until upd_mfma overwrites)
    ushort_t* Pb = (ushort_t*)(out + NR + NT);
    float* molf  = out + NR + NT;

    const int* srcp = ei;
    const int* dstp = ei + E;
    int nbN = (N + 255) / 256;

    convert_w<<<nbN, 256, 0, stream>>>(W_node, W_att1, W_upd, Wy1, Wa1,
                                       Wnb, W1tb, W1mb, Wub, Wy1b, Wa1b, counts, N);
    encode_pq<<<(N + 63) / 64, 256, 0, stream>>>(mol_x, Wnb, b_node, W1tb, W1mb, b_att1,
                                                 QH, Pb, dstp, counts, N, E);
    scan1<<<nbN, 256, 0, stream>>>(counts, offs, partials, N);
    scan_add<<<nbN, 256, 0, stream>>>(offs, cursor, partials, nbN, N);
    fill_csr<<<(E + 255) / 256, 256, 0, stream>>>(srcp, dstp, cursor, csrc, E);
    fused_gather<<<nbG, 256, 0, stream>>>(Pb, QH, pos, csrc, offs, counts,
                                          W_att1 + 256 * 128, W_att2, b_att2,
                                          Ab, m_n, redm, rede, N);
    combine<<<1, 256, 0, stream>>>(redm, rede, scal, nbG);
    upd_mfma<<<(N + 15) / 16, 256, 0, stream>>>(Ab, m_n, scal, Wub, b_upd, molf, N);
    head_mfma<<<(NR + NT) / 16, 256, 0, stream>>>(reaction_x, target_x, Wnb, b_node,
                                                  Wy1b, by1, Wy2, by2, Wa1b, ba1, Wa2, ba2,
                                                  out, NR / 16, NR, NT);
}

// Round 9
// 246.905 us; speedup vs baseline: 1.0854x; 1.0854x over previous
//
#include <hip/hip_runtime.h>
#include <hip/hip_bf16.h>

typedef unsigned short ushort_t;
typedef __attribute__((ext_vector_type(8))) short s16x8;
typedef __attribute__((ext_vector_type(4))) float f32x4;

__device__ inline unsigned short f2bf(float x) {
    unsigned u = __float_as_uint(x);
    return (unsigned short)((u + 0x7FFFu + ((u >> 16) & 1u)) >> 16);
}
__device__ inline float bflo(unsigned u) { return __uint_as_float(u << 16); }
__device__ inline float bfhi(unsigned u) { return __uint_as_float(u & 0xffff0000u); }

// ---------------------------------------------------------------------------
// convert_w: pack weights into MFMA B-fragment order (bf16). Also zeroes counts.
// ---------------------------------------------------------------------------
__device__ inline void pack_one(const float* __restrict__ W, int K, int N,
                                ushort_t* __restrict__ dst, int g) {
    int KT = K / 32;
    int nt = g / (KT * 64);
    int rem = g % (KT * 64);
    int kt = rem / 64, lane = rem % 64;
    int n = nt * 16 + (lane & 15);
    int kbase = kt * 32 + ((lane >> 4) << 3);
    ushort_t tmp[8];
#pragma unroll
    for (int j = 0; j < 8; ++j) tmp[j] = f2bf(W[(size_t)(kbase + j) * N + n]);
    uint4 pk;
    pk.x = tmp[0] | ((unsigned)tmp[1] << 16);
    pk.y = tmp[2] | ((unsigned)tmp[3] << 16);
    pk.z = tmp[4] | ((unsigned)tmp[5] << 16);
    pk.w = tmp[6] | ((unsigned)tmp[7] << 16);
    *(uint4*)&dst[(size_t)g * 8] = pk;
}

__global__ void convert_w(const float* __restrict__ Wn, const float* __restrict__ W1,
                          const float* __restrict__ Wu, const float* __restrict__ Wy1,
                          const float* __restrict__ Wa1,
                          ushort_t* __restrict__ Wnb, ushort_t* __restrict__ W1tb,
                          ushort_t* __restrict__ W1mb, ushort_t* __restrict__ Wub,
                          ushort_t* __restrict__ Wy1b, ushort_t* __restrict__ Wa1b,
                          int* __restrict__ counts, int N) {
    int t = blockIdx.x * 256 + threadIdx.x;
    if (t < 1024)       pack_one(Wn, 64, 128, Wnb, t);
    else if (t < 3072)  pack_one(W1, 128, 128, W1tb, t - 1024);
    else if (t < 5120)  pack_one(W1 + 128 * 128, 128, 128, W1mb, t - 3072);
    else if (t < 7168)  pack_one(Wu, 128, 128, Wub, t - 5120);
    else if (t < 8192)  pack_one(Wy1, 128, 64, Wy1b, t - 7168);
    else if (t < 9216)  pack_one(Wa1, 128, 64, Wa1b, t - 8192);
    if (t < N) counts[t] = 0;
}

// ---------------------------------------------------------------------------
// encode_pq: 64 rows/block, wave owns 16 rows. x A-frags direct from global;
// h C-layout -> LDS -> A-frags -> P,Q. Fused dst histogram (grid-stride).
// ---------------------------------------------------------------------------
__global__ void encode_pq(const float* __restrict__ x, const ushort_t* __restrict__ Wnb,
                          const float* __restrict__ bn, const ushort_t* __restrict__ W1tb,
                          const ushort_t* __restrict__ W1mb, const float* __restrict__ b1,
                          ushort_t* __restrict__ hb, ushort_t* __restrict__ P,
                          ushort_t* __restrict__ Q, const int* __restrict__ dst,
                          int* __restrict__ counts, int nrows, int E) {
    __shared__ ushort_t ldsH[4 * 16 * 136];
    int t = threadIdx.x;
    // fused dst histogram
    for (int e = blockIdx.x * 256 + t; e < E; e += gridDim.x * 256)
        atomicAdd(&counts[dst[e]], 1);
    int w = t >> 6, lane = t & 63;
    int c = lane & 15, q = lane >> 4;
    int r0 = blockIdx.x * 64 + w * 16;
    int rowA = r0 + c; if (rowA >= nrows) rowA = nrows - 1;
    ushort_t* myH = &ldsH[w * 16 * 136];

    s16x8 xa[2];
#pragma unroll
    for (int kt = 0; kt < 2; ++kt) {
        const float* xp = &x[(size_t)rowA * 64 + kt * 32 + q * 8];
        float4 v0 = *(const float4*)xp;
        float4 v1 = *(const float4*)(xp + 4);
        s16x8 a;
        a[0] = (short)f2bf(v0.x); a[1] = (short)f2bf(v0.y);
        a[2] = (short)f2bf(v0.z); a[3] = (short)f2bf(v0.w);
        a[4] = (short)f2bf(v1.x); a[5] = (short)f2bf(v1.y);
        a[6] = (short)f2bf(v1.z); a[7] = (short)f2bf(v1.w);
        xa[kt] = a;
    }
#pragma unroll
    for (int nt = 0; nt < 8; ++nt) {
        f32x4 acc = {0.f, 0.f, 0.f, 0.f};
#pragma unroll
        for (int kt = 0; kt < 2; ++kt) {
            s16x8 b = *(const s16x8*)&Wnb[((nt * 2 + kt) * 64 + lane) * 8];
            acc = __builtin_amdgcn_mfma_f32_16x16x32_bf16(xa[kt], b, acc, 0, 0, 0);
        }
        float bi = bn[nt * 16 + c];
#pragma unroll
        for (int r = 0; r < 4; ++r) {
            int row = r0 + q * 4 + r;
            ushort_t hv = f2bf(acc[r] + bi);
            myH[(q * 4 + r) * 136 + nt * 16 + c] = hv;
            if (row < nrows) hb[(size_t)row * 128 + nt * 16 + c] = hv;
        }
    }
    __syncthreads();
    s16x8 ha[4];
#pragma unroll
    for (int kt = 0; kt < 4; ++kt)
        ha[kt] = *(const s16x8*)&myH[c * 136 + kt * 32 + q * 8];
#pragma unroll
    for (int nt = 0; nt < 8; ++nt) {
        f32x4 pa = {0.f, 0.f, 0.f, 0.f}, qa = pa;
#pragma unroll
        for (int kt = 0; kt < 4; ++kt) {
            s16x8 bp = *(const s16x8*)&W1tb[((nt * 4 + kt) * 64 + lane) * 8];
            s16x8 bq = *(const s16x8*)&W1mb[((nt * 4 + kt) * 64 + lane) * 8];
            pa = __builtin_amdgcn_mfma_f32_16x16x32_bf16(ha[kt], bp, pa, 0, 0, 0);
            qa = __builtin_amdgcn_mfma_f32_16x16x32_bf16(ha[kt], bq, qa, 0, 0, 0);
        }
        float bi = b1[nt * 16 + c];
#pragma unroll
        for (int r = 0; r < 4; ++r) {
            int row = r0 + q * 4 + r;
            if (row < nrows) {
                P[(size_t)row * 128 + nt * 16 + c] = f2bf(pa[r] + bi);
                Q[(size_t)row * 128 + nt * 16 + c] = f2bf(qa[r]);
            }
        }
    }
}

// ---------------------------------------------------------------------------
// CSR scan: scan1 + scan_add (offs -> cursor init)
// ---------------------------------------------------------------------------
__global__ void scan1(const int* __restrict__ counts, int* __restrict__ offs,
                      int* __restrict__ partials, int N) {
    __shared__ int sm[256];
    int i = blockIdx.x * 256 + threadIdx.x;
    int v = (i < N) ? counts[i] : 0;
    sm[threadIdx.x] = v; __syncthreads();
    for (int off = 1; off < 256; off <<= 1) {
        int add = (threadIdx.x >= off) ? sm[threadIdx.x - off] : 0;
        __syncthreads();
        sm[threadIdx.x] += add;
        __syncthreads();
    }
    if (i < N) offs[i] = sm[threadIdx.x] - v;
    if (threadIdx.x == 255) partials[blockIdx.x] = sm[255];
}

__global__ void scan_add(int* __restrict__ offs, int* __restrict__ cursor,
                         const int* __restrict__ partials, int nb, int N) {
    __shared__ int sm[256];
    int t = threadIdx.x;
    sm[t] = (t < nb && t < blockIdx.x) ? partials[t] : 0;
    __syncthreads();
    for (int off = 128; off > 0; off >>= 1) {
        if (t < off) sm[t] += sm[t + off];
        __syncthreads();
    }
    int basev = sm[0];
    int i = blockIdx.x * 256 + t;
    if (i < N) {
        int v = offs[i] + basev;
        offs[i] = v;
        cursor[i] = v;
    }
}

// ---------------------------------------------------------------------------
// edge_score: 16 lanes/edge, 8 cols/lane, 4 edges/wave/iter. Computes score,
// claims CSR slot, writes csr[p]=(src, s_bits) directly. Fused per-block
// online-softmax partials. No s[] array, no separate fill pass.
// ---------------------------------------------------------------------------
__global__ void edge_score(const ushort_t* __restrict__ P, const ushort_t* __restrict__ Q,
                           const float* __restrict__ pos, const int* __restrict__ src,
                           const int* __restrict__ dst, const float* __restrict__ W1b,
                           const float* __restrict__ W2, const float* __restrict__ b2,
                           int* __restrict__ cursor, int2* __restrict__ csr,
                           float* __restrict__ redm, float* __restrict__ rede, int E) {
    __shared__ float wsh[512];
    __shared__ float smm[256], sme[256];
    int t = threadIdx.x;
    for (int i = t; i < 384; i += 256) wsh[i] = W1b[i];
    if (t < 128) wsh[384 + t] = W2[t];
    __syncthreads();
    int w = t >> 6, lane = t & 63;
    int g = lane >> 4, c = lane & 15;
    float w0[8], w1[8], w2[8], wv[8];
#pragma unroll
    for (int j = 0; j < 8; ++j) {
        w0[j] = wsh[c * 8 + j];
        w1[j] = wsh[128 + c * 8 + j];
        w2[j] = wsh[256 + c * 8 + j];
        wv[j] = wsh[384 + c * 8 + j];
    }
    float b2v = b2[0];
    int base = blockIdx.x * 64 + w * 16;
    float m = -1e30f, ev = 0.f;
#pragma unroll
    for (int it = 0; it < 4; ++it) {
        int e = base + it * 4 + g;
        bool valid = e < E;
        int ee = valid ? e : (E - 1);
        int sa = src[ee], da = dst[ee];
        uint4 pr = *(const uint4*)&P[(size_t)da * 128 + c * 8];
        uint4 qr = *(const uint4*)&Q[(size_t)sa * 128 + c * 8];
        float d0 = pos[da * 3]     - pos[sa * 3];
        float d1 = pos[da * 3 + 1] - pos[sa * 3 + 1];
        float d2 = pos[da * 3 + 2] - pos[sa * 3 + 2];
        unsigned pw[4] = {pr.x, pr.y, pr.z, pr.w};
        unsigned qw[4] = {qr.x, qr.y, qr.z, qr.w};
        float v = 0.f;
#pragma unroll
        for (int jj = 0; jj < 4; ++jj) {
            float pe = bflo(pw[jj]) + bflo(qw[jj])
                     + d0 * w0[2 * jj] + d1 * w1[2 * jj] + d2 * w2[2 * jj];
            float po = bfhi(pw[jj]) + bfhi(qw[jj])
                     + d0 * w0[2 * jj + 1] + d1 * w1[2 * jj + 1] + d2 * w2[2 * jj + 1];
            v += fmaxf(pe, 0.f) * wv[2 * jj] + fmaxf(po, 0.f) * wv[2 * jj + 1];
        }
#pragma unroll
        for (int off = 1; off < 16; off <<= 1) v += __shfl_xor(v, off, 64);
        if (c == 0 && valid) {
            float sv = v + b2v;
            int p = atomicAdd(&cursor[da], 1);
            csr[p] = make_int2(sa, __float_as_int(sv));
            float nm = fmaxf(m, sv);
            ev = ev * __expf(m - nm) + __expf(sv - nm);
            m = nm;
        }
    }
    smm[t] = m; sme[t] = ev; __syncthreads();
    for (int off = 128; off > 0; off >>= 1) {
        if (t < off) {
            float m1 = smm[t], m2 = smm[t + off];
            float e1 = sme[t], e2 = sme[t + off];
            float M = fmaxf(m1, m2);
            smm[t] = M;
            sme[t] = e1 * __expf(m1 - M) + e2 * __expf(m2 - M);
        }
        __syncthreads();
    }
    if (t == 0) { redm[blockIdx.x] = smm[0]; rede[blockIdx.x] = sme[0]; }
}

// single block combines nb online-softmax partials
__global__ void smax2(const float* __restrict__ redm, const float* __restrict__ rede,
                      float* __restrict__ scal, int nb) {
    __shared__ float smm[256], sme[256];
    int t = threadIdx.x;
    float m = -1e30f, ev = 0.f;
    for (int i = t; i < nb; i += 256) {
        float m2 = redm[i], e2 = rede[i];
        float M = fmaxf(m, m2);
        ev = ev * __expf(m - M) + e2 * __expf(m2 - M);
        m = M;
    }
    smm[t] = m; sme[t] = ev; __syncthreads();
    for (int off = 128; off > 0; off >>= 1) {
        if (t < off) {
            float m1 = smm[t], m2 = smm[t + off];
            float e1 = sme[t], e2 = sme[t + off];
            float M = fmaxf(m1, m2);
            smm[t] = M;
            sme[t] = e1 * __expf(m1 - M) + e2 * __expf(m2 - M);
        }
        __syncthreads();
    }
    if (t == 0) { scal[0] = smm[0]; scal[1] = 1.f / sme[0]; }
}

// ---------------------------------------------------------------------------
// gather_upd: 16 nodes/block, wave per 4 nodes, quarter-wave per edge
// (4 edges in flight, 8 cols/lane). csr (src,s) read sequentially. Then MFMA.
// ---------------------------------------------------------------------------
__global__ void gather_upd(const ushort_t* __restrict__ hb, const int2* __restrict__ csr,
                           const int* __restrict__ offs, const int* __restrict__ deg,
                           const float* __restrict__ scal,
                           const ushort_t* __restrict__ Wub, const float* __restrict__ bu,
                           float* __restrict__ C, int N) {
    __shared__ ushort_t ldsA[16 * 136];
    int t = threadIdx.x;
    int w = t >> 6, lane = t & 63;
    int g = lane >> 4, c = lane & 15;
    int r0 = blockIdx.x * 16;
    float m = scal[0], inv = scal[1];
#pragma unroll
    for (int i = 0; i < 4; ++i) {
        int node = r0 + w * 4 + i;
        float a[8] = {0.f, 0.f, 0.f, 0.f, 0.f, 0.f, 0.f, 0.f};
        if (node < N) {
            int start = offs[node], d = deg[node];
            for (int k = g; k < d; k += 4) {
                int2 v = csr[start + k];
                float att = __expf(__int_as_float(v.y) - m) * inv;
                uint4 hq = *(const uint4*)&hb[(size_t)v.x * 128 + c * 8];
                a[0] += bflo(hq.x) * att; a[1] += bfhi(hq.x) * att;
                a[2] += bflo(hq.y) * att; a[3] += bfhi(hq.y) * att;
                a[4] += bflo(hq.z) * att; a[5] += bfhi(hq.z) * att;
                a[6] += bflo(hq.w) * att; a[7] += bfhi(hq.w) * att;
            }
        }
#pragma unroll
        for (int j = 0; j < 8; ++j) {
            a[j] += __shfl_xor(a[j], 16, 64);
            a[j] += __shfl_xor(a[j], 32, 64);
        }
        if (g == 0) {
            uint4 pk;
            pk.x = f2bf(a[0]) | ((unsigned)f2bf(a[1]) << 16);
            pk.y = f2bf(a[2]) | ((unsigned)f2bf(a[3]) << 16);
            pk.z = f2bf(a[4]) | ((unsigned)f2bf(a[5]) << 16);
            pk.w = f2bf(a[6]) | ((unsigned)f2bf(a[7]) << 16);
            *(uint4*)&ldsA[(w * 4 + i) * 136 + c * 8] = pk;
        }
    }
    __syncthreads();
    int q = lane >> 4;
    int ntA = w, ntB = w + 4;
    f32x4 acc0 = {0.f, 0.f, 0.f, 0.f}, acc1 = acc0;
#pragma unroll
    for (int kt = 0; kt < 4; ++kt) {
        s16x8 av = *(const s16x8*)&ldsA[c * 136 + kt * 32 + q * 8];
        s16x8 b0 = *(const s16x8*)&Wub[((ntA * 4 + kt) * 64 + lane) * 8];
        s16x8 b1 = *(const s16x8*)&Wub[((ntB * 4 + kt) * 64 + lane) * 8];
        acc0 = __builtin_amdgcn_mfma_f32_16x16x32_bf16(av, b0, acc0, 0, 0, 0);
        acc1 = __builtin_amdgcn_mfma_f32_16x16x32_bf16(av, b1, acc1, 0, 0, 0);
    }
    float bi0 = bu[ntA * 16 + c], bi1 = bu[ntB * 16 + c];
#pragma unroll
    for (int r = 0; r < 4; ++r) {
        int row = r0 + q * 4 + r;
        if (row < N) {
            C[(size_t)row * 128 + ntA * 16 + c] = acc0[r] + bi0;
            C[(size_t)row * 128 + ntB * 16 + c] = acc1[r] + bi1;
        }
    }
}

// ---------------------------------------------------------------------------
// head_mfma: out[r] = relu((x@Wn+bn)@W1+b1) . W2 + b2, fused, 16 rows/block
// ---------------------------------------------------------------------------
__global__ void head_mfma(const float* __restrict__ rx, const float* __restrict__ tx,
                          const ushort_t* __restrict__ Wnb, const float* __restrict__ bn,
                          const ushort_t* __restrict__ Wy1b, const float* __restrict__ by1,
                          const float* __restrict__ Wy2, const float* __restrict__ by2,
                          const ushort_t* __restrict__ Wa1b, const float* __restrict__ ba1,
                          const float* __restrict__ Wa2, const float* __restrict__ ba2,
                          float* __restrict__ out, int nb1, int NR, int NT) {
    __shared__ ushort_t ldsA[16 * 72];
    __shared__ ushort_t ldsB[16 * 136];
    __shared__ float part[64];
    int blk = blockIdx.x;
    const float* x; const ushort_t* W1b; const float* b1; const float* W2; const float* b2;
    float* o; int r0, nrows;
    if (blk < nb1) { x = rx; W1b = Wy1b; b1 = by1; W2 = Wy2; b2 = by2; o = out; r0 = blk * 16; nrows = NR; }
    else { x = tx; W1b = Wa1b; b1 = ba1; W2 = Wa2; b2 = ba2; o = out + NR; r0 = (blk - nb1) * 16; nrows = NT; }

    int t = threadIdx.x;
    {
        int row = t >> 4, c4 = (t & 15) * 4;
        float4 v = *(const float4*)&x[(size_t)(r0 + row) * 64 + c4];
        uint2 pk;
        pk.x = f2bf(v.x) | ((unsigned)f2bf(v.y) << 16);
        pk.y = f2bf(v.z) | ((unsigned)f2bf(v.w) << 16);
        *(uint2*)&ldsA[row * 72 + c4] = pk;
    }
    __syncthreads();
    int w = t >> 6, lane = t & 63;
    int c = lane & 15, q = lane >> 4;
    {
        int ntA = w, ntB = w + 4;
        f32x4 acc0 = {0.f, 0.f, 0.f, 0.f}, acc1 = acc0;
#pragma unroll
        for (int kt = 0; kt < 2; ++kt) {
            s16x8 a = *(const s16x8*)&ldsA[c * 72 + kt * 32 + q * 8];
            s16x8 b0 = *(const s16x8*)&Wnb[((ntA * 2 + kt) * 64 + lane) * 8];
            s16x8 b1v = *(const s16x8*)&Wnb[((ntB * 2 + kt) * 64 + lane) * 8];
            acc0 = __builtin_amdgcn_mfma_f32_16x16x32_bf16(a, b0, acc0, 0, 0, 0);
            acc1 = __builtin_amdgcn_mfma_f32_16x16x32_bf16(a, b1v, acc1, 0, 0, 0);
        }
        float bi0 = bn[ntA * 16 + c], bi1 = bn[ntB * 16 + c];
#pragma unroll
        for (int r = 0; r < 4; ++r) {
            int row = q * 4 + r;
            ldsB[row * 136 + ntA * 16 + c] = f2bf(acc0[r] + bi0);
            ldsB[row * 136 + ntB * 16 + c] = f2bf(acc1[r] + bi1);
        }
    }
    __syncthreads();
    {
        f32x4 acc = {0.f, 0.f, 0.f, 0.f};
#pragma unroll
        for (int kt = 0; kt < 4; ++kt) {
            s16x8 a = *(const s16x8*)&ldsB[c * 136 + kt * 32 + q * 8];
            s16x8 b0 = *(const s16x8*)&W1b[((w * 4 + kt) * 64 + lane) * 8];
            acc = __builtin_amdgcn_mfma_f32_16x16x32_bf16(a, b0, acc, 0, 0, 0);
        }
        float bi = b1[w * 16 + c], w2v = W2[w * 16 + c];
#pragma unroll
        for (int r = 0; r < 4; ++r) {
            float u = fmaxf(acc[r] + bi, 0.f) * w2v;
#pragma unroll
            for (int mm = 1; mm < 16; mm <<= 1) u += __shfl_xor(u, mm, 64);
            if (c == 0) part[w * 16 + q * 4 + r] = u;
        }
    }
    __syncthreads();
    if (t < 16) {
        int row = r0 + t;
        if (row < nrows)
            o[row] = part[t] + part[16 + t] + part[32 + t] + part[48 + t] + b2[0];
    }
}

extern "C" void kernel_launch(void* const* d_in, const int* in_sizes, int n_in,
                              void* d_out, int out_size, void* d_ws, size_t ws_size,
                              hipStream_t stream) {
    const float* mol_x      = (const float*)d_in[0];
    const float* pos        = (const float*)d_in[1];
    const float* reaction_x = (const float*)d_in[2];
    const float* target_x   = (const float*)d_in[3];
    const int*   ei         = (const int*)d_in[4];
    const float* W_node = (const float*)d_in[5];
    const float* b_node = (const float*)d_in[6];
    const float* W_att1 = (const float*)d_in[7];
    const float* b_att1 = (const float*)d_in[8];
    const float* W_att2 = (const float*)d_in[9];
    const float* b_att2 = (const float*)d_in[10];
    const float* W_upd  = (const float*)d_in[11];
    const float* b_upd  = (const float*)d_in[12];
    const float* Wy1 = (const float*)d_in[13];
    const float* by1 = (const float*)d_in[14];
    const float* Wy2 = (const float*)d_in[15];
    const float* by2 = (const float*)d_in[16];
    const float* Wa1 = (const float*)d_in[17];
    const float* ba1 = (const float*)d_in[18];
    const float* Wa2 = (const float*)d_in[19];
    const float* ba2 = (const float*)d_in[20];

    int N  = in_sizes[0] / 64;
    int E  = in_sizes[4] / 2;
    int NR = in_sizes[2] / 64;
    int NT = in_sizes[3] / 64;

    float* out = (float*)d_out;

    int nbE = (E + 63) / 64;     // edge_score blocks / softmax partials

    // ws layout
    char* wp = (char*)d_ws;
    ushort_t* hb = (ushort_t*)wp;  wp += (size_t)N * 128 * 2;
    ushort_t* Qb = (ushort_t*)wp;  wp += (size_t)N * 128 * 2;
    float* redm  = (float*)wp;     wp += (size_t)nbE * 4;
    float* rede  = (float*)wp;     wp += (size_t)nbE * 4;
    float* scal  = (float*)wp;     wp += 4 * 4;
    int* counts  = (int*)wp;       wp += (size_t)N * 4;
    int* offs    = (int*)wp;       wp += (size_t)N * 4;
    int* cursor  = (int*)wp;       wp += (size_t)N * 4;
    int* partials= (int*)wp;       wp += 256 * 4;
    int2* csr    = (int2*)wp;      wp += (size_t)E * 8;
    ushort_t* Wnb  = (ushort_t*)wp; wp += 8192 * 2;
    ushort_t* W1tb = (ushort_t*)wp; wp += 16384 * 2;
    ushort_t* W1mb = (ushort_t*)wp; wp += 16384 * 2;
    ushort_t* Wub  = (ushort_t*)wp; wp += 16384 * 2;
    ushort_t* Wy1b = (ushort_t*)wp; wp += 8192 * 2;
    ushort_t* Wa1b = (ushort_t*)wp; wp += 8192 * 2;
    // P lives in the mol_feats output region (dead before gather_upd writes it)
    ushort_t* Pb = (ushort_t*)(out + NR + NT);
    float* molf  = out + NR + NT;

    const int* srcp = ei;
    const int* dstp = ei + E;
    int nbN = (N + 255) / 256;

    convert_w<<<nbN, 256, 0, stream>>>(W_node, W_att1, W_upd, Wy1, Wa1,
                                       Wnb, W1tb, W1mb, Wub, Wy1b, Wa1b, counts, N);
    encode_pq<<<(N + 63) / 64, 256, 0, stream>>>(mol_x, Wnb, b_node, W1tb, W1mb, b_att1,
                                                 hb, Pb, Qb, dstp, counts, N, E);
    scan1<<<nbN, 256, 0, stream>>>(counts, offs, partials, N);
    scan_add<<<nbN, 256, 0, stream>>>(offs, cursor, partials, nbN, N);
    edge_score<<<nbE, 256, 0, stream>>>(Pb, Qb, pos, srcp, dstp,
                                        W_att1 + 256 * 128, W_att2, b_att2,
                                        cursor, csr, redm, rede, E);
    smax2<<<1, 256, 0, stream>>>(redm, rede, scal, nbE);
    gather_upd<<<(N + 15) / 16, 256, 0, stream>>>(hb, csr, offs, counts, scal,
                                                  Wub, b_upd, molf, N);
    head_mfma<<<(NR + NT) / 16, 256, 0, stream>>>(reaction_x, target_x, Wnb, b_node,
                                                  Wy1b, by1, Wy2, by2, Wa1b, ba1, Wa2, ba2,
                                                  out, NR / 16, NR, NT);
}

// Round 10
// 232.281 us; speedup vs baseline: 1.1537x; 1.0630x over previous
//
#include <hip/hip_runtime.h>
#include <hip/hip_bf16.h>

typedef unsigned short ushort_t;
typedef __attribute__((ext_vector_type(8))) short s16x8;
typedef __attribute__((ext_vector_type(4))) float f32x4;

__device__ inline unsigned short f2bf(float x) {
    unsigned u = __float_as_uint(x);
    return (unsigned short)((u + 0x7FFFu + ((u >> 16) & 1u)) >> 16);
}
__device__ inline float bflo(unsigned u) { return __uint_as_float(u << 16); }
__device__ inline float bfhi(unsigned u) { return __uint_as_float(u & 0xffff0000u); }

// ---------------------------------------------------------------------------
// convert_w: pack weights into MFMA B-fragment order (bf16). Also zeroes counts.
// ---------------------------------------------------------------------------
__device__ inline void pack_one(const float* __restrict__ W, int K, int N,
                                ushort_t* __restrict__ dst, int g) {
    int KT = K / 32;
    int nt = g / (KT * 64);
    int rem = g % (KT * 64);
    int kt = rem / 64, lane = rem % 64;
    int n = nt * 16 + (lane & 15);
    int kbase = kt * 32 + ((lane >> 4) << 3);
    ushort_t tmp[8];
#pragma unroll
    for (int j = 0; j < 8; ++j) tmp[j] = f2bf(W[(size_t)(kbase + j) * N + n]);
    uint4 pk;
    pk.x = tmp[0] | ((unsigned)tmp[1] << 16);
    pk.y = tmp[2] | ((unsigned)tmp[3] << 16);
    pk.z = tmp[4] | ((unsigned)tmp[5] << 16);
    pk.w = tmp[6] | ((unsigned)tmp[7] << 16);
    *(uint4*)&dst[(size_t)g * 8] = pk;
}

__global__ void convert_w(const float* __restrict__ Wn, const float* __restrict__ W1,
                          const float* __restrict__ Wu, const float* __restrict__ Wy1,
                          const float* __restrict__ Wa1,
                          ushort_t* __restrict__ Wnb, ushort_t* __restrict__ W1tb,
                          ushort_t* __restrict__ W1mb, ushort_t* __restrict__ Wub,
                          ushort_t* __restrict__ Wy1b, ushort_t* __restrict__ Wa1b,
                          int* __restrict__ counts, int N) {
    int t = blockIdx.x * 256 + threadIdx.x;
    if (t < 1024)       pack_one(Wn, 64, 128, Wnb, t);
    else if (t < 3072)  pack_one(W1, 128, 128, W1tb, t - 1024);
    else if (t < 5120)  pack_one(W1 + 128 * 128, 128, 128, W1mb, t - 3072);
    else if (t < 7168)  pack_one(Wu, 128, 128, Wub, t - 5120);
    else if (t < 8192)  pack_one(Wy1, 128, 64, Wy1b, t - 7168);
    else if (t < 9216)  pack_one(Wa1, 128, 64, Wa1b, t - 8192);
    if (t < N) counts[t] = 0;
}

// ---------------------------------------------------------------------------
// encode_pq: 64 rows/block, wave owns 16 rows. x A-frags direct from global;
// h C-layout -> LDS -> A-frags -> P,Q. Fused dst histogram (grid-stride).
// ---------------------------------------------------------------------------
__global__ void encode_pq(const float* __restrict__ x, const ushort_t* __restrict__ Wnb,
                          const float* __restrict__ bn, const ushort_t* __restrict__ W1tb,
                          const ushort_t* __restrict__ W1mb, const float* __restrict__ b1,
                          ushort_t* __restrict__ hb, ushort_t* __restrict__ P,
                          ushort_t* __restrict__ Q, const int* __restrict__ dst,
                          int* __restrict__ counts, int nrows, int E) {
    __shared__ ushort_t ldsH[4 * 16 * 136];
    int t = threadIdx.x;
    for (int e = blockIdx.x * 256 + t; e < E; e += gridDim.x * 256)
        atomicAdd(&counts[dst[e]], 1);
    int w = t >> 6, lane = t & 63;
    int c = lane & 15, q = lane >> 4;
    int r0 = blockIdx.x * 64 + w * 16;
    int rowA = r0 + c; if (rowA >= nrows) rowA = nrows - 1;
    ushort_t* myH = &ldsH[w * 16 * 136];

    s16x8 xa[2];
#pragma unroll
    for (int kt = 0; kt < 2; ++kt) {
        const float* xp = &x[(size_t)rowA * 64 + kt * 32 + q * 8];
        float4 v0 = *(const float4*)xp;
        float4 v1 = *(const float4*)(xp + 4);
        s16x8 a;
        a[0] = (short)f2bf(v0.x); a[1] = (short)f2bf(v0.y);
        a[2] = (short)f2bf(v0.z); a[3] = (short)f2bf(v0.w);
        a[4] = (short)f2bf(v1.x); a[5] = (short)f2bf(v1.y);
        a[6] = (short)f2bf(v1.z); a[7] = (short)f2bf(v1.w);
        xa[kt] = a;
    }
#pragma unroll
    for (int nt = 0; nt < 8; ++nt) {
        f32x4 acc = {0.f, 0.f, 0.f, 0.f};
#pragma unroll
        for (int kt = 0; kt < 2; ++kt) {
            s16x8 b = *(const s16x8*)&Wnb[((nt * 2 + kt) * 64 + lane) * 8];
            acc = __builtin_amdgcn_mfma_f32_16x16x32_bf16(xa[kt], b, acc, 0, 0, 0);
        }
        float bi = bn[nt * 16 + c];
#pragma unroll
        for (int r = 0; r < 4; ++r) {
            int row = r0 + q * 4 + r;
            ushort_t hv = f2bf(acc[r] + bi);
            myH[(q * 4 + r) * 136 + nt * 16 + c] = hv;
            if (row < nrows) hb[(size_t)row * 128 + nt * 16 + c] = hv;
        }
    }
    __syncthreads();
    s16x8 ha[4];
#pragma unroll
    for (int kt = 0; kt < 4; ++kt)
        ha[kt] = *(const s16x8*)&myH[c * 136 + kt * 32 + q * 8];
#pragma unroll
    for (int nt = 0; nt < 8; ++nt) {
        f32x4 pa = {0.f, 0.f, 0.f, 0.f}, qa = pa;
#pragma unroll
        for (int kt = 0; kt < 4; ++kt) {
            s16x8 bp = *(const s16x8*)&W1tb[((nt * 4 + kt) * 64 + lane) * 8];
            s16x8 bq = *(const s16x8*)&W1mb[((nt * 4 + kt) * 64 + lane) * 8];
            pa = __builtin_amdgcn_mfma_f32_16x16x32_bf16(ha[kt], bp, pa, 0, 0, 0);
            qa = __builtin_amdgcn_mfma_f32_16x16x32_bf16(ha[kt], bq, qa, 0, 0, 0);
        }
        float bi = b1[nt * 16 + c];
#pragma unroll
        for (int r = 0; r < 4; ++r) {
            int row = r0 + q * 4 + r;
            if (row < nrows) {
                P[(size_t)row * 128 + nt * 16 + c] = f2bf(pa[r] + bi);
                Q[(size_t)row * 128 + nt * 16 + c] = f2bf(qa[r]);
            }
        }
    }
}

// ---------------------------------------------------------------------------
// CSR scan: scan1 + scan_add (offs -> cursor init)
// ---------------------------------------------------------------------------
__global__ void scan1(const int* __restrict__ counts, int* __restrict__ offs,
                      int* __restrict__ partials, int N) {
    __shared__ int sm[256];
    int i = blockIdx.x * 256 + threadIdx.x;
    int v = (i < N) ? counts[i] : 0;
    sm[threadIdx.x] = v; __syncthreads();
    for (int off = 1; off < 256; off <<= 1) {
        int add = (threadIdx.x >= off) ? sm[threadIdx.x - off] : 0;
        __syncthreads();
        sm[threadIdx.x] += add;
        __syncthreads();
    }
    if (i < N) offs[i] = sm[threadIdx.x] - v;
    if (threadIdx.x == 255) partials[blockIdx.x] = sm[255];
}

__global__ void scan_add(int* __restrict__ offs, int* __restrict__ cursor,
                         const int* __restrict__ partials, int nb, int N) {
    __shared__ int sm[256];
    int t = threadIdx.x;
    sm[t] = (t < nb && t < blockIdx.x) ? partials[t] : 0;
    __syncthreads();
    for (int off = 128; off > 0; off >>= 1) {
        if (t < off) sm[t] += sm[t + off];
        __syncthreads();
    }
    int basev = sm[0];
    int i = blockIdx.x * 256 + t;
    if (i < N) {
        int v = offs[i] + basev;
        offs[i] = v;
        cursor[i] = v;
    }
}

// ---------------------------------------------------------------------------
// edge_score: 128 edges/block; 16 lanes/edge, 8 cols/lane, 4 edges/wave/iter.
// CSR slot claimed BEFORE the score compute (atomic off critical path);
// csr[p]=(src, s_bits) written at the end. Per-block online-softmax partials.
// ---------------------------------------------------------------------------
__global__ void edge_score(const ushort_t* __restrict__ P, const ushort_t* __restrict__ Q,
                           const float* __restrict__ pos, const int* __restrict__ src,
                           const int* __restrict__ dst, const float* __restrict__ W1b,
                           const float* __restrict__ W2, const float* __restrict__ b2,
                           int* __restrict__ cursor, int2* __restrict__ csr,
                           float* __restrict__ redm, float* __restrict__ rede, int E) {
    __shared__ float wsh[512];
    __shared__ float smm[256], sme[256];
    int t = threadIdx.x;
    for (int i = t; i < 384; i += 256) wsh[i] = W1b[i];
    if (t < 128) wsh[384 + t] = W2[t];
    __syncthreads();
    int w = t >> 6, lane = t & 63;
    int g = lane >> 4, c = lane & 15;
    float w0[8], w1[8], w2[8], wv[8];
#pragma unroll
    for (int j = 0; j < 8; ++j) {
        w0[j] = wsh[c * 8 + j];
        w1[j] = wsh[128 + c * 8 + j];
        w2[j] = wsh[256 + c * 8 + j];
        wv[j] = wsh[384 + c * 8 + j];
    }
    float b2v = b2[0];
    int base = blockIdx.x * 128 + w * 32;
    float m = -1e30f, ev = 0.f;
#pragma unroll
    for (int it = 0; it < 8; ++it) {
        int e = base + it * 4 + g;
        bool valid = e < E;
        int ee = valid ? e : (E - 1);
        int sa = src[ee], da = dst[ee];
        int p = 0;
        if (c == 0 && valid) p = atomicAdd(&cursor[da], 1);   // off critical path
        uint4 pr = *(const uint4*)&P[(size_t)da * 128 + c * 8];
        uint4 qr = *(const uint4*)&Q[(size_t)sa * 128 + c * 8];
        float d0 = pos[da * 3]     - pos[sa * 3];
        float d1 = pos[da * 3 + 1] - pos[sa * 3 + 1];
        float d2 = pos[da * 3 + 2] - pos[sa * 3 + 2];
        unsigned pw[4] = {pr.x, pr.y, pr.z, pr.w};
        unsigned qw[4] = {qr.x, qr.y, qr.z, qr.w};
        float v = 0.f;
#pragma unroll
        for (int jj = 0; jj < 4; ++jj) {
            float pe = bflo(pw[jj]) + bflo(qw[jj])
                     + d0 * w0[2 * jj] + d1 * w1[2 * jj] + d2 * w2[2 * jj];
            float po = bfhi(pw[jj]) + bfhi(qw[jj])
                     + d0 * w0[2 * jj + 1] + d1 * w1[2 * jj + 1] + d2 * w2[2 * jj + 1];
            v += fmaxf(pe, 0.f) * wv[2 * jj] + fmaxf(po, 0.f) * wv[2 * jj + 1];
        }
#pragma unroll
        for (int off = 1; off < 16; off <<= 1) v += __shfl_xor(v, off, 64);
        if (c == 0 && valid) {
            float sv = v + b2v;
            csr[p] = make_int2(sa, __float_as_int(sv));
            float nm = fmaxf(m, sv);
            ev = ev * __expf(m - nm) + __expf(sv - nm);
            m = nm;
        }
    }
    smm[t] = m; sme[t] = ev; __syncthreads();
    for (int off = 128; off > 0; off >>= 1) {
        if (t < off) {
            float m1 = smm[t], m2 = smm[t + off];
            float e1 = sme[t], e2 = sme[t + off];
            float M = fmaxf(m1, m2);
            smm[t] = M;
            sme[t] = e1 * __expf(m1 - M) + e2 * __expf(m2 - M);
        }
        __syncthreads();
    }
    if (t == 0) { redm[blockIdx.x] = smm[0]; rede[blockIdx.x] = sme[0]; }
}

// ---------------------------------------------------------------------------
// gather_head: blocks [0,nbG): gather+upd (each block locally combines the
// (m,Z) partials -> M, 1/Z). Blocks [nbG,..): fused prediction heads.
// ---------------------------------------------------------------------------
__global__ void gather_head(const ushort_t* __restrict__ hb, const int2* __restrict__ csr,
                            const int* __restrict__ offs, const int* __restrict__ deg,
                            const float* __restrict__ redm, const float* __restrict__ rede,
                            int nbE,
                            const ushort_t* __restrict__ Wub, const float* __restrict__ bu,
                            float* __restrict__ molf, int N, int nbG,
                            const float* __restrict__ rx, const float* __restrict__ tx,
                            const ushort_t* __restrict__ Wnb, const float* __restrict__ bn,
                            const ushort_t* __restrict__ Wy1b, const float* __restrict__ by1,
                            const float* __restrict__ Wy2, const float* __restrict__ by2,
                            const ushort_t* __restrict__ Wa1b, const float* __restrict__ ba1,
                            const float* __restrict__ Wa2, const float* __restrict__ ba2,
                            float* __restrict__ out, int nb1, int NR, int NT) {
    int t = threadIdx.x;
    int w = t >> 6, lane = t & 63;
    int c = lane & 15, q = lane >> 4;

    if (blockIdx.x < nbG) {
        // ------------------ gather + upd ------------------
        __shared__ ushort_t ldsA[16 * 136];
        __shared__ float smm[256], sme[256];
        // local combine of global-softmax partials
        float m = -1e30f, z = 0.f;
        for (int i = t; i < nbE; i += 256) {
            float m2 = redm[i], z2 = rede[i];
            float M = fmaxf(m, m2);
            z = z * __expf(m - M) + z2 * __expf(m2 - M);
            m = M;
        }
        smm[t] = m; sme[t] = z; __syncthreads();
        for (int off = 128; off > 0; off >>= 1) {
            if (t < off) {
                float m1 = smm[t], m2 = smm[t + off];
                float e1 = sme[t], e2 = sme[t + off];
                float M = fmaxf(m1, m2);
                smm[t] = M;
                sme[t] = e1 * __expf(m1 - M) + e2 * __expf(m2 - M);
            }
            __syncthreads();
        }
        float gm = smm[0], inv = 1.f / sme[0];
        __syncthreads();

        int g = lane >> 4;
        int r0 = blockIdx.x * 16;
#pragma unroll
        for (int i = 0; i < 4; ++i) {
            int node = r0 + w * 4 + i;
            float a[8] = {0.f, 0.f, 0.f, 0.f, 0.f, 0.f, 0.f, 0.f};
            if (node < N) {
                int start = offs[node], d = deg[node];
                int k = g;
                for (; k + 4 < d; k += 8) {   // 2 edges in flight per quarter-wave
                    int2 v0 = csr[start + k];
                    int2 v1 = csr[start + k + 4];
                    uint4 h0 = *(const uint4*)&hb[(size_t)v0.x * 128 + c * 8];
                    uint4 h1 = *(const uint4*)&hb[(size_t)v1.x * 128 + c * 8];
                    float at0 = __expf(__int_as_float(v0.y) - gm) * inv;
                    float at1 = __expf(__int_as_float(v1.y) - gm) * inv;
                    a[0] += bflo(h0.x) * at0; a[1] += bfhi(h0.x) * at0;
                    a[2] += bflo(h0.y) * at0; a[3] += bfhi(h0.y) * at0;
                    a[4] += bflo(h0.z) * at0; a[5] += bfhi(h0.z) * at0;
                    a[6] += bflo(h0.w) * at0; a[7] += bfhi(h0.w) * at0;
                    a[0] += bflo(h1.x) * at1; a[1] += bfhi(h1.x) * at1;
                    a[2] += bflo(h1.y) * at1; a[3] += bfhi(h1.y) * at1;
                    a[4] += bflo(h1.z) * at1; a[5] += bfhi(h1.z) * at1;
                    a[6] += bflo(h1.w) * at1; a[7] += bfhi(h1.w) * at1;
                }
                if (k < d) {
                    int2 v0 = csr[start + k];
                    uint4 h0 = *(const uint4*)&hb[(size_t)v0.x * 128 + c * 8];
                    float at0 = __expf(__int_as_float(v0.y) - gm) * inv;
                    a[0] += bflo(h0.x) * at0; a[1] += bfhi(h0.x) * at0;
                    a[2] += bflo(h0.y) * at0; a[3] += bfhi(h0.y) * at0;
                    a[4] += bflo(h0.z) * at0; a[5] += bfhi(h0.z) * at0;
                    a[6] += bflo(h0.w) * at0; a[7] += bfhi(h0.w) * at0;
                }
            }
#pragma unroll
            for (int j = 0; j < 8; ++j) {
                a[j] += __shfl_xor(a[j], 16, 64);
                a[j] += __shfl_xor(a[j], 32, 64);
            }
            if (g == 0) {
                uint4 pk;
                pk.x = f2bf(a[0]) | ((unsigned)f2bf(a[1]) << 16);
                pk.y = f2bf(a[2]) | ((unsigned)f2bf(a[3]) << 16);
                pk.z = f2bf(a[4]) | ((unsigned)f2bf(a[5]) << 16);
                pk.w = f2bf(a[6]) | ((unsigned)f2bf(a[7]) << 16);
                *(uint4*)&ldsA[(w * 4 + i) * 136 + c * 8] = pk;
            }
        }
        __syncthreads();
        int ntA = w, ntB = w + 4;
        f32x4 acc0 = {0.f, 0.f, 0.f, 0.f}, acc1 = acc0;
#pragma unroll
        for (int kt = 0; kt < 4; ++kt) {
            s16x8 av = *(const s16x8*)&ldsA[c * 136 + kt * 32 + q * 8];
            s16x8 b0 = *(const s16x8*)&Wub[((ntA * 4 + kt) * 64 + lane) * 8];
            s16x8 b1 = *(const s16x8*)&Wub[((ntB * 4 + kt) * 64 + lane) * 8];
            acc0 = __builtin_amdgcn_mfma_f32_16x16x32_bf16(av, b0, acc0, 0, 0, 0);
            acc1 = __builtin_amdgcn_mfma_f32_16x16x32_bf16(av, b1, acc1, 0, 0, 0);
        }
        float bi0 = bu[ntA * 16 + c], bi1 = bu[ntB * 16 + c];
#pragma unroll
        for (int r = 0; r < 4; ++r) {
            int row = r0 + q * 4 + r;
            if (row < N) {
                molf[(size_t)row * 128 + ntA * 16 + c] = acc0[r] + bi0;
                molf[(size_t)row * 128 + ntB * 16 + c] = acc1[r] + bi1;
            }
        }
    } else {
        // ------------------ prediction heads ------------------
        __shared__ ushort_t ldsX[16 * 72];
        __shared__ ushort_t ldsB[16 * 136];
        __shared__ float part[64];
        int blk = blockIdx.x - nbG;
        const float* x; const ushort_t* W1b; const float* b1; const float* W2; const float* b2;
        float* o; int r0, nrows;
        if (blk < nb1) { x = rx; W1b = Wy1b; b1 = by1; W2 = Wy2; b2 = by2; o = out; r0 = blk * 16; nrows = NR; }
        else { x = tx; W1b = Wa1b; b1 = ba1; W2 = Wa2; b2 = ba2; o = out + NR; r0 = (blk - nb1) * 16; nrows = NT; }
        {
            int row = t >> 4, c4 = (t & 15) * 4;
            float4 v = *(const float4*)&x[(size_t)(r0 + row) * 64 + c4];
            uint2 pk;
            pk.x = f2bf(v.x) | ((unsigned)f2bf(v.y) << 16);
            pk.y = f2bf(v.z) | ((unsigned)f2bf(v.w) << 16);
            *(uint2*)&ldsX[row * 72 + c4] = pk;
        }
        __syncthreads();
        {
            int ntA = w, ntB = w + 4;
            f32x4 acc0 = {0.f, 0.f, 0.f, 0.f}, acc1 = acc0;
#pragma unroll
            for (int kt = 0; kt < 2; ++kt) {
                s16x8 a = *(const s16x8*)&ldsX[c * 72 + kt * 32 + q * 8];
                s16x8 b0 = *(const s16x8*)&Wnb[((ntA * 2 + kt) * 64 + lane) * 8];
                s16x8 b1v = *(const s16x8*)&Wnb[((ntB * 2 + kt) * 64 + lane) * 8];
                acc0 = __builtin_amdgcn_mfma_f32_16x16x32_bf16(a, b0, acc0, 0, 0, 0);
                acc1 = __builtin_amdgcn_mfma_f32_16x16x32_bf16(a, b1v, acc1, 0, 0, 0);
            }
            float bi0 = bn[ntA * 16 + c], bi1 = bn[ntB * 16 + c];
#pragma unroll
            for (int r = 0; r < 4; ++r) {
                int row = q * 4 + r;
                ldsB[row * 136 + ntA * 16 + c] = f2bf(acc0[r] + bi0);
                ldsB[row * 136 + ntB * 16 + c] = f2bf(acc1[r] + bi1);
            }
        }
        __syncthreads();
        {
            f32x4 acc = {0.f, 0.f, 0.f, 0.f};
#pragma unroll
            for (int kt = 0; kt < 4; ++kt) {
                s16x8 a = *(const s16x8*)&ldsB[c * 136 + kt * 32 + q * 8];
                s16x8 b0 = *(const s16x8*)&W1b[((w * 4 + kt) * 64 + lane) * 8];
                acc = __builtin_amdgcn_mfma_f32_16x16x32_bf16(a, b0, acc, 0, 0, 0);
            }
            float bi = b1[w * 16 + c], w2v = W2[w * 16 + c];
#pragma unroll
            for (int r = 0; r < 4; ++r) {
                float u = fmaxf(acc[r] + bi, 0.f) * w2v;
#pragma unroll
                for (int mm = 1; mm < 16; mm <<= 1) u += __shfl_xor(u, mm, 64);
                if (c == 0) part[w * 16 + q * 4 + r] = u;
            }
        }
        __syncthreads();
        if (t < 16) {
            int row = r0 + t;
            if (row < nrows)
                o[row] = part[t] + part[16 + t] + part[32 + t] + part[48 + t] + b2[0];
        }
    }
}

extern "C" void kernel_launch(void* const* d_in, const int* in_sizes, int n_in,
                              void* d_out, int out_size, void* d_ws, size_t ws_size,
                              hipStream_t stream) {
    const float* mol_x      = (const float*)d_in[0];
    const float* pos        = (const float*)d_in[1];
    const float* reaction_x = (const float*)d_in[2];
    const float* target_x   = (const float*)d_in[3];
    const int*   ei         = (const int*)d_in[4];
    const float* W_node = (const float*)d_in[5];
    const float* b_node = (const float*)d_in[6];
    const float* W_att1 = (const float*)d_in[7];
    const float* b_att1 = (const float*)d_in[8];
    const float* W_att2 = (const float*)d_in[9];
    const float* b_att2 = (const float*)d_in[10];
    const float* W_upd  = (const float*)d_in[11];
    const float* b_upd  = (const float*)d_in[12];
    const float* Wy1 = (const float*)d_in[13];
    const float* by1 = (const float*)d_in[14];
    const float* Wy2 = (const float*)d_in[15];
    const float* by2 = (const float*)d_in[16];
    const float* Wa1 = (const float*)d_in[17];
    const float* ba1 = (const float*)d_in[18];
    const float* Wa2 = (const float*)d_in[19];
    const float* ba2 = (const float*)d_in[20];

    int N  = in_sizes[0] / 64;
    int E  = in_sizes[4] / 2;
    int NR = in_sizes[2] / 64;
    int NT = in_sizes[3] / 64;

    float* out = (float*)d_out;

    int nbE = (E + 127) / 128;   // edge_score blocks / softmax partials
    int nbG = (N + 15) / 16;     // gather blocks
    int nbH = (NR + NT) / 16;    // head blocks

    // ws layout
    char* wp = (char*)d_ws;
    ushort_t* hb = (ushort_t*)wp;  wp += (size_t)N * 128 * 2;
    ushort_t* Qb = (ushort_t*)wp;  wp += (size_t)N * 128 * 2;
    float* redm  = (float*)wp;     wp += (size_t)nbE * 4;
    float* rede  = (float*)wp;     wp += (size_t)nbE * 4;
    int* counts  = (int*)wp;       wp += (size_t)N * 4;
    int* offs    = (int*)wp;       wp += (size_t)N * 4;
    int* cursor  = (int*)wp;       wp += (size_t)N * 4;
    int* partials= (int*)wp;       wp += 256 * 4;
    int2* csr    = (int2*)wp;      wp += (size_t)E * 8;
    ushort_t* Wnb  = (ushort_t*)wp; wp += 8192 * 2;
    ushort_t* W1tb = (ushort_t*)wp; wp += 16384 * 2;
    ushort_t* W1mb = (ushort_t*)wp; wp += 16384 * 2;
    ushort_t* Wub  = (ushort_t*)wp; wp += 16384 * 2;
    ushort_t* Wy1b = (ushort_t*)wp; wp += 8192 * 2;
    ushort_t* Wa1b = (ushort_t*)wp; wp += 8192 * 2;
    // P lives in the mol_feats output region (dead before gather writes it)
    ushort_t* Pb = (ushort_t*)(out + NR + NT);
    float* molf  = out + NR + NT;

    const int* srcp = ei;
    const int* dstp = ei + E;
    int nbN = (N + 255) / 256;

    convert_w<<<nbN, 256, 0, stream>>>(W_node, W_att1, W_upd, Wy1, Wa1,
                                       Wnb, W1tb, W1mb, Wub, Wy1b, Wa1b, counts, N);
    encode_pq<<<(N + 63) / 64, 256, 0, stream>>>(mol_x, Wnb, b_node, W1tb, W1mb, b_att1,
                                                 hb, Pb, Qb, dstp, counts, N, E);
    scan1<<<nbN, 256, 0, stream>>>(counts, offs, partials, N);
    scan_add<<<nbN, 256, 0, stream>>>(offs, cursor, partials, nbN, N);
    edge_score<<<nbE, 256, 0, stream>>>(Pb, Qb, pos, srcp, dstp,
                                        W_att1 + 256 * 128, W_att2, b_att2,
                                        cursor, csr, redm, rede, E);
    gather_head<<<nbG + nbH, 256, 0, stream>>>(hb, csr, offs, counts, redm, rede, nbE,
                                               Wub, b_upd, molf, N, nbG,
                                               reaction_x, target_x, Wnb, b_node,
                                               Wy1b, by1, Wy2, by2, Wa1b, ba1, Wa2, ba2,
                                               out, NR / 16, NR, NT);
}